// Round 8
// baseline (164.798 us; speedup 1.0000x reference)
//
#include <hip/hip_runtime.h>

// SAModule (PointNet++ SA), fused f32-input kernel. R13:
//  - R12 post-mortem: residency is capped at ~3 blocks/CU regardless of LDS in the
//    32-48KB range (R12's 4x32KB never reached 16 waves), but R5 PROVED 2x64KB blocks
//    co-reside. Kernel is latency-bound at ~63% SIMD issue with ~12 waves/CU.
//  - R13 (single change): 8-wave / 512-thread / 8-center blocks, 64KB LDS => 2 blocks/CU
//    = 16 waves/CU using the proven-resident block shape. Phase A tests 8 centers over
//    half the points (per-thread cost ~equal); all per-wave phases unchanged.

typedef unsigned short u16;
typedef unsigned int u32;
typedef unsigned long long u64;
typedef __bf16 bf16x8 __attribute__((ext_vector_type(8)));
typedef float floatx4 __attribute__((ext_vector_type(4)));

#define PCLOUD 4096
#define DIN    64
#define MCENT  8192
#define KNBR   32
#define CAP    448
#define WAVES  8

// smem map (65536 B): sA = 256 rows x 256B. phase A/B overlay (dead before gather):
#define OFF_LIST  0        // u64[8][CAP] = 28672
#define OFF_HIST  28672    // u32[8][32]  = 1024
#define OFF_NBRL  29696    // int[8][32]  = 1024
#define OFF_CNT   30720    // int[8] acnt | int[8] cnt2
#define OFF_CEN   30784    // float4[8] centers (x,y,z,|c|^2)
#define OFF_BCL   30912    // int[8] cloud ids

__device__ inline u16 f2bf(float f) {          // RNE, no scrub (inputs finite)
    u32 b = __float_as_uint(f);
    b += 0x7fffu + ((b >> 16) & 1u);
    return (u16)(b >> 16);
}
__device__ inline u32 cvtpk(float a, float b) {  // packed {bf16(a), bf16(b)<<16}, RNE
    u32 r;
    asm("v_cvt_pk_bf16_f32 %0, %1, %2" : "=v"(r) : "v"(a), "v"(b));
    return r;
}
__device__ inline u64 wave_min_u64(u64 v) {
    #pragma unroll
    for (int off = 32; off; off >>= 1) {
        u64 o = __shfl_xor((unsigned long long)v, off);
        if (o < v) v = o;
    }
    return v;
}
__device__ inline u64 d2key(float d2, int j) {
    u32 u = __float_as_uint(d2);
    u = (u & 0x80000000u) ? ~u : (u | 0x80000000u);   // order-preserving map
    return ((u64)u << 32) | (u32)j;
}
// density-equalized bucket: uniform points => count/bucket ~ const. Monotone in d2.
__device__ inline int key_bucket(u64 k) {
    u32 hi = (u32)(k >> 32);
    if (hi < 0x80000000u) return 0;                    // d2 <= -0
    float d2 = __uint_as_float(hi & 0x7fffffffu);
    float t = d2 * 25.0f;                              // d2/R2, [0,1]
    float b = 32.0f * t * __builtin_sqrtf(t);          // 32 * t^1.5
    int bi = (int)b;
    return bi > 31 ? 31 : (bi < 0 ? 0 : bi);
}

// ---- prep: weights -> bf16 B-fragment images in ws (consumed directly from L2) ----
// 32 contiguous 4KB blocks of 16 cols each: blk 0..7 = W1, 8..15 = W2, 16..31 = W3.
// blk layout (256 uint4): chunk[n*16 + (kc^(n&7))] = {bf16 W[kc*8+j][col0+n], j=0..7}
__global__ void prep_kernel(const float* __restrict__ W1, const float* __restrict__ W2,
                            const float* __restrict__ W3, uint4* __restrict__ ws) {
    int t = blockIdx.x * 256 + threadIdx.x;   // 0..8191
    int g = t >> 11, r = t & 2047;
    int n = r >> 4, kc = r & 15;
    const float* W; int rs, n0, krows;
    if (g == 0)      { W = W1; rs = 128; n0 = 0;   krows = 67;  }
    else if (g == 1) { W = W2; rs = 128; n0 = 0;   krows = 128; }
    else if (g == 2) { W = W3; rs = 256; n0 = 0;   krows = 128; }
    else             { W = W3; rs = 256; n0 = 128; krows = 128; }
    u16 e[8];
    #pragma unroll
    for (int j = 0; j < 8; j++) {
        int k = kc * 8 + j;
        e[j] = (k < krows) ? f2bf(W[(size_t)k * rs + n0 + n]) : (u16)0;
    }
    ws[(g << 11) + (n << 4) + (kc ^ (n & 7))] = *(const uint4*)e;
}

// One B-fragment (8 bf16 of col `col0+m16`, k-rows cb*8..cb*8+7), straight from ws/L2.
__device__ __forceinline__ uint4 ldB_ws(const uint4* __restrict__ ws4, int blk, int cb, int m16) {
    return ws4[blk * 256 + (m16 << 4) + (cb ^ (m16 & 7))];
}
// Workspace-less fallback: gather the column from W in f32 and pack (correctness path).
__device__ __forceinline__ uint4 ldB_fb(const float* __restrict__ W, int rs, int col,
                                        int cb, int krows) {
    u16 e[8];
    #pragma unroll
    for (int j = 0; j < 8; j++) {
        int k = cb * 8 + j;
        e[j] = (k < krows) ? f2bf(W[(size_t)k * rs + col]) : (u16)0;
    }
    return *(const uint4*)e;
}

__device__ __forceinline__ void push_hit(int c, float d2, int j,
                                         int* acnt, u64* lists) {
    int p = atomicAdd(&acnt[c], 1);
    if (p < CAP) lists[c * CAP + p] = d2key(d2, j);
}

template <bool WS>
__global__ __launch_bounds__(512, 4) void sa_kernel(
    const float* __restrict__ x, const float* __restrict__ pos,
    const int* __restrict__ batch, const int* __restrict__ idx,
    const float* __restrict__ W1, const float* __restrict__ b1,
    const float* __restrict__ W2, const float* __restrict__ b2,
    const float* __restrict__ W3, const float* __restrict__ b3,
    const uint4* __restrict__ ws4, float* __restrict__ out) {
    __shared__ __align__(16) char smem[65536];
    u64*  lists = (u64*)(smem + OFF_LIST);
    u32*  hist  = (u32*)(smem + OFF_HIST);
    int*  nbrl  = (int*)(smem + OFF_NBRL);
    int*  acnt  = (int*)(smem + OFF_CNT);
    int*  cnt2  = (int*)(smem + OFF_CNT + 32);
    float4* cen = (float4*)(smem + OFF_CEN);
    int*  bcls  = (int*)(smem + OFF_BCL);
    uint4* sA4  = (uint4*)smem;

    int tid = threadIdx.x, w = tid >> 6, l = tid & 63;
    int bid = blockIdx.x;
    int m0 = ((bid & 7) << 10) + ((bid >> 3) << 3);   // XCD-friendly: bid%8 ~ cloud
    int m = m0 + w;
    int ic = idx[m] & (8 * PCLOUD - 1);
    float cx = pos[ic * 3], cy = pos[ic * 3 + 1], cz = pos[ic * 3 + 2];
    float sc = __fadd_rn(__fadd_rn(__fmul_rn(cx, cx), __fmul_rn(cy, cy)), __fmul_rn(cz, cz));
    int bcl = batch[ic] & 7;
    int base = bcl << 12;
    const float R2 = 0.04f;

    if (l == 0) { cen[w] = make_float4(cx, cy, cz, sc); bcls[w] = bcl; }
    if (tid < WAVES) { acnt[tid] = 0; cnt2[tid] = 0; }
    if (l == 1) {
        float* o1 = out + MCENT * 256;
        o1[m * 3] = cx; o1[m * 3 + 1] = cy; o1[m * 3 + 2] = cz;
        (o1 + MCENT * 3)[m] = (float)bcl;
    }
    __syncthreads();

    // ---- phase A: cooperative scan, float4 loads, FMA-contracted tests vs 8 centers ----
    bool uni = true;
    #pragma unroll
    for (int cc = 1; cc < WAVES; cc++) uni = uni && (bcls[cc] == bcls[0]);
    if (uni) {
        float4 cw[WAVES];
        float nx[WAVES], ny[WAVES], nz[WAVES];
        #pragma unroll
        for (int cc = 0; cc < WAVES; cc++) {
            cw[cc] = cen[cc];
            nx[cc] = -2.0f * cw[cc].x; ny[cc] = -2.0f * cw[cc].y; nz[cc] = -2.0f * cw[cc].z;
        }
        int jb = bcls[0] << 12;
        const float4* pb4 = (const float4*)(pos + (size_t)jb * 3);

#define TESTP(PX, PY, PZ, J) { \
    float sp = __builtin_fmaf((PX), (PX), __builtin_fmaf((PY), (PY), (PZ) * (PZ))); \
    _Pragma("unroll") \
    for (int cc = 0; cc < WAVES; cc++) { \
        float d2 = __builtin_fmaf(nx[cc], (PX), __builtin_fmaf(ny[cc], (PY), \
                   __builtin_fmaf(nz[cc], (PZ), cw[cc].w + sp))); \
        if (d2 <= R2) push_hit(cc, d2, (J), acnt, lists); \
    } }

        #pragma unroll
        for (int it = 0; it < 2; it++) {
            int tq = it * 512 + tid;                   // quad-point index 0..1023
            float4 q0 = pb4[tq * 3], q1 = pb4[tq * 3 + 1], q2 = pb4[tq * 3 + 2];
            int j0 = jb + tq * 4;
            TESTP(q0.x, q0.y, q0.z, j0)
            TESTP(q0.w, q1.x, q1.y, j0 + 1)
            TESTP(q1.z, q1.w, q2.x, j0 + 2)
            TESTP(q2.y, q2.z, q2.w, j0 + 3)
        }
#undef TESTP
    } else {
        // rare mixed-cloud block: per-wave scan of own cloud from global (FMA form)
        float nx = -2.0f * cx, ny = -2.0f * cy, nz = -2.0f * cz;
        for (int t = l; t < PCLOUD; t += 64) {
            int j = base + t;
            float px = pos[j * 3], py = pos[j * 3 + 1], pz = pos[j * 3 + 2];
            float sp = __builtin_fmaf(px, px, __builtin_fmaf(py, py, pz * pz));
            float d2 = __builtin_fmaf(nx, px, __builtin_fmaf(ny, py,
                       __builtin_fmaf(nz, pz, sc + sp)));
            if (d2 <= R2) push_hit(w, d2, j, acnt, lists);
        }
    }
    __syncthreads();   // cross-wave list visibility

    int c = acnt[w];
    int nsel = c < KNBR ? c : KNBR;
    u64* mylist = lists + w * CAP;

    // ---- phase B: select the 32 smallest (d2,idx) keys (set only; order free) ----
    int selj = -1;
    if (c <= KNBR) {
        if (l < c) selj = (int)(u32)mylist[l];
    } else if (c <= CAP) {
        u64 kk[7];
        int bk[7];
        if (l < 32) hist[w * 32 + l] = 0;              // same-wave LDS: ordered
        #pragma unroll
        for (int i = 0; i < 7; i++) kk[i] = (l + i * 64 < c) ? mylist[l + i * 64] : ~0ull;
        #pragma unroll
        for (int i = 0; i < 7; i++) {                  // build d2 histogram (this wave only)
            bk[i] = 32;
            if (kk[i] != ~0ull) {
                bk[i] = key_bucket(kk[i]);
                atomicAdd(&hist[w * 32 + bk[i]], 1u);
            }
        }
        int hv = (l < 32) ? (int)hist[w * 32 + l] : 0; // atomics above are same-wave: ordered
        #pragma unroll
        for (int off = 1; off <= 16; off <<= 1) {   // inclusive scan, lanes 0..31
            int o = __shfl_up(hv, off);
            if (l >= off) hv += o;
        }
        u64 ge = __ballot((l < 32) && (hv >= KNBR));
        int B = __ffsll((unsigned long long)ge) - 1;        // threshold bucket
        int S = (B == 0) ? 0 : __shfl(hv, B - 1);           // count strictly below B
        #pragma unroll
        for (int i = 0; i < 7; i++) {                       // bulk-select below B
            if (kk[i] != ~0ull) {
                if (bk[i] < B) { int p = atomicAdd(&cnt2[w], 1); nbrl[w * 32 + p] = (int)(u32)kk[i]; }
                if (bk[i] != B) kk[i] = ~0ull;              // keep only bucket-B keys
            }
        }
        int need = KNBR - S;                                // equalized buckets: ~1-4 rounds
        u64 last = 0;
        for (int r = 0; r < need; r++) {
            u64 mn = ~0ull;
            #pragma unroll
            for (int i = 0; i < 7; i++) if (kk[i] > last && kk[i] < mn) mn = kk[i];
            mn = wave_min_u64(mn);
            if (l == 0) nbrl[w * 32 + S + r] = (int)(u32)mn;
            last = mn;
        }
        if (l < KNBR) selj = nbrl[w * 32 + l];
    } else {
        // overflow fallback (never taken for uniform data): streaming 32-round argmin
        float nx = -2.0f * cx, ny = -2.0f * cy, nz = -2.0f * cz;
        u64 last = 0;
        for (int r = 0; r < KNBR; r++) {
            u64 mn = ~0ull;
            for (int t = l; t < PCLOUD; t += 64) {
                int j = base + t;
                float px = pos[j * 3], py = pos[j * 3 + 1], pz = pos[j * 3 + 2];
                float sp = __builtin_fmaf(px, px, __builtin_fmaf(py, py, pz * pz));
                float d2 = __builtin_fmaf(nx, px, __builtin_fmaf(ny, py,
                           __builtin_fmaf(nz, pz, sc + sp)));
                if (d2 <= R2) { u64 kf = d2key(d2, j); if (kf > last && kf < mn) mn = kf; }
            }
            mn = wave_min_u64(mn);
            if (l == r) selj = (int)(u32)mn;
            last = mn;
        }
    }
    __syncthreads();   // LAST barrier: lists/hist dead; sA becomes the (wave-private) A-tile

    // ---- gather 32 feat rows per wave (XOR 16B-chunk swizzle); rows are wave-private.
    //      h-branched compile-time unroll: all x loads issue together (no serial chain).
    {
        int h = l & 1, rl = l >> 1;
        int row = w * 32 + rl;
        int j = __shfl(selj, rl);
        int xv = row & 7;
        uint4* dst = sA4 + row * 16;
        uint4 z; z.x = z.y = z.z = z.w = 0;
        if (j >= 0) {
            const float4* sx = (const float4*)(x + (size_t)j * DIN);
            if (h == 0) {
                float4 f[12];
                #pragma unroll
                for (int i = 0; i < 12; i++) f[i] = sx[i];
                #pragma unroll
                for (int c0 = 0; c0 < 6; c0++) {
                    uint4 pv;
                    pv.x = cvtpk(f[c0 * 2].x, f[c0 * 2].y);
                    pv.y = cvtpk(f[c0 * 2].z, f[c0 * 2].w);
                    pv.z = cvtpk(f[c0 * 2 + 1].x, f[c0 * 2 + 1].y);
                    pv.w = cvtpk(f[c0 * 2 + 1].z, f[c0 * 2 + 1].w);
                    dst[c0 ^ xv] = pv;
                }
            } else {
                float4 f[4];
                #pragma unroll
                for (int i = 0; i < 4; i++) f[i] = sx[12 + i];
                float rx = pos[j * 3] - cx, ry = pos[j * 3 + 1] - cy, rz = pos[j * 3 + 2] - cz;
                #pragma unroll
                for (int c0 = 0; c0 < 2; c0++) {
                    uint4 pv;
                    pv.x = cvtpk(f[c0 * 2].x, f[c0 * 2].y);
                    pv.y = cvtpk(f[c0 * 2].z, f[c0 * 2].w);
                    pv.z = cvtpk(f[c0 * 2 + 1].x, f[c0 * 2 + 1].y);
                    pv.w = cvtpk(f[c0 * 2 + 1].z, f[c0 * 2 + 1].w);
                    dst[(6 + c0) ^ xv] = pv;
                }
                uint4 rc; rc.x = cvtpk(rx, ry); rc.y = cvtpk(rz, 0.0f); rc.z = 0; rc.w = 0;
                dst[8 ^ xv] = rc;
                dst[9 ^ xv] = z; dst[10 ^ xv] = z; dst[11 ^ xv] = z;
            }
        } else {
            if (h == 0) {
                #pragma unroll
                for (int c0 = 0; c0 < 6; c0++) dst[c0 ^ xv] = z;
            } else {
                #pragma unroll
                for (int c0 = 6; c0 < 12; c0++) dst[c0 ^ xv] = z;
            }
        }
    }

    int m16 = l & 15, quad = l >> 4;
    int r0 = w * 32;
    const floatx4 vzero = {0.f, 0.f, 0.f, 0.f};

#define LDB(BLK, CB, W, RS, COL, KR) \
    (WS ? ldB_ws(ws4, (BLK), (CB), m16) : ldB_fb((W), (RS), (COL), (CB), (KR)))

// h-epilogue for GEMM1/2: relu(acc+bias) -> bf16 pair writes into swizzled sA rows
#define EPI12(BPTR, S, ACC) { \
    float4 bb = ((const float4*)(BPTR))[(S) * 4 + quad]; \
    _Pragma("unroll") \
    for (int t = 0; t < 2; t++) { \
        int rr = r0 + t * 16 + m16; \
        uint2 pv; \
        pv.x = cvtpk(fmaxf(ACC[t][0] + bb.x, 0.f), fmaxf(ACC[t][1] + bb.y, 0.f)); \
        pv.y = cvtpk(fmaxf(ACC[t][2] + bb.z, 0.f), fmaxf(ACC[t][3] + bb.w, 0.f)); \
        *(uint2*)(smem + rr * 256 + ((((S) * 2 + (quad >> 1)) ^ (rr & 7)) << 4) + ((quad & 1) << 3)) = pv; \
    } }

    // ==== GEMM1: h1 = relu(feat @ W1 + b1), K=96, swapped operands, 8 steps, 2-deep ====
    {
        bf16x8 a1[3][2];
        #pragma unroll
        for (int ki = 0; ki < 3; ki++)
            #pragma unroll
            for (int t = 0; t < 2; t++) {
                int row = r0 + t * 16 + m16;
                a1[ki][t] = __builtin_bit_cast(bf16x8, sA4[row * 16 + ((ki * 4 + quad) ^ (row & 7))]);
            }
        uint4 p0[3], p1[3];
        #pragma unroll
        for (int ki = 0; ki < 3; ki++) p0[ki] = LDB(0, ki * 4 + quad, W1, 128, m16, 67);
        #pragma unroll
        for (int ki = 0; ki < 3; ki++) p1[ki] = LDB(1, ki * 4 + quad, W1, 128, 16 + m16, 67);
        #pragma unroll
        for (int s = 0; s < 8; s += 2) {
            {
                floatx4 acc[2] = {vzero, vzero};
                __builtin_amdgcn_s_setprio(1);
                #pragma unroll
                for (int ki = 0; ki < 3; ki++) {
                    bf16x8 b = __builtin_bit_cast(bf16x8, p0[ki]);
                    #pragma unroll
                    for (int t = 0; t < 2; t++)
                        acc[t] = __builtin_amdgcn_mfma_f32_16x16x32_bf16(b, a1[ki][t], acc[t], 0, 0, 0);
                }
                __builtin_amdgcn_s_setprio(0);
                if (s + 2 < 8) {
                    #pragma unroll
                    for (int ki = 0; ki < 3; ki++)
                        p0[ki] = LDB(s + 2, ki * 4 + quad, W1, 128, (s + 2) * 16 + m16, 67);
                }
                EPI12(b1, s, acc);
            }
            {
                floatx4 acc[2] = {vzero, vzero};
                __builtin_amdgcn_s_setprio(1);
                #pragma unroll
                for (int ki = 0; ki < 3; ki++) {
                    bf16x8 b = __builtin_bit_cast(bf16x8, p1[ki]);
                    #pragma unroll
                    for (int t = 0; t < 2; t++)
                        acc[t] = __builtin_amdgcn_mfma_f32_16x16x32_bf16(b, a1[ki][t], acc[t], 0, 0, 0);
                }
                __builtin_amdgcn_s_setprio(0);
                if (s + 3 < 8) {
                    #pragma unroll
                    for (int ki = 0; ki < 3; ki++)
                        p1[ki] = LDB(s + 3, ki * 4 + quad, W1, 128, (s + 3) * 16 + m16, 67);
                }
                EPI12(b1, s + 1, acc);
            }
        }
    }

    // ==== GEMM2: h2 = relu(h1 @ W2 + b2), K=128, swapped operands, 8 steps, 2-deep ====
    {
        bf16x8 a2[4][2];
        #pragma unroll
        for (int ki = 0; ki < 4; ki++)
            #pragma unroll
            for (int t = 0; t < 2; t++) {
                int row = r0 + t * 16 + m16;
                a2[ki][t] = __builtin_bit_cast(bf16x8, sA4[row * 16 + ((ki * 4 + quad) ^ (row & 7))]);
            }
        uint4 p0[4], p1[4];
        #pragma unroll
        for (int ki = 0; ki < 4; ki++) p0[ki] = LDB(8, ki * 4 + quad, W2, 128, m16, 128);
        #pragma unroll
        for (int ki = 0; ki < 4; ki++) p1[ki] = LDB(9, ki * 4 + quad, W2, 128, 16 + m16, 128);
        #pragma unroll
        for (int s = 0; s < 8; s += 2) {
            {
                floatx4 acc[2] = {vzero, vzero};
                __builtin_amdgcn_s_setprio(1);
                #pragma unroll
                for (int ki = 0; ki < 4; ki++) {
                    bf16x8 b = __builtin_bit_cast(bf16x8, p0[ki]);
                    #pragma unroll
                    for (int t = 0; t < 2; t++)
                        acc[t] = __builtin_amdgcn_mfma_f32_16x16x32_bf16(b, a2[ki][t], acc[t], 0, 0, 0);
                }
                __builtin_amdgcn_s_setprio(0);
                if (s + 2 < 8) {
                    #pragma unroll
                    for (int ki = 0; ki < 4; ki++)
                        p0[ki] = LDB(8 + s + 2, ki * 4 + quad, W2, 128, (s + 2) * 16 + m16, 128);
                }
                EPI12(b2, s, acc);
            }
            {
                floatx4 acc[2] = {vzero, vzero};
                __builtin_amdgcn_s_setprio(1);
                #pragma unroll
                for (int ki = 0; ki < 4; ki++) {
                    bf16x8 b = __builtin_bit_cast(bf16x8, p1[ki]);
                    #pragma unroll
                    for (int t = 0; t < 2; t++)
                        acc[t] = __builtin_amdgcn_mfma_f32_16x16x32_bf16(b, a2[ki][t], acc[t], 0, 0, 0);
                }
                __builtin_amdgcn_s_setprio(0);
                if (s + 3 < 8) {
                    #pragma unroll
                    for (int ki = 0; ki < 4; ki++)
                        p1[ki] = LDB(8 + s + 3, ki * 4 + quad, W2, 128, (s + 3) * 16 + m16, 128);
                }
                EPI12(b2, s + 1, acc);
            }
        }
    }

// GEMM3 epilogue: masked max over this wave's 32 rows, reduce across quads, store
#define EPI3(S, ACC) { \
    int col = (S) * 16 + m16; \
    float bias = b3[col]; \
    float mv = 0.0f; \
    _Pragma("unroll") \
    for (int t = 0; t < 2; t++) \
        _Pragma("unroll") \
        for (int i = 0; i < 4; i++) { \
            int k = t * 16 + quad * 4 + i; \
            float v = fmaxf(ACC[t][i] + bias, 0.0f); \
            if (k < nsel) mv = fmaxf(mv, v); \
        } \
    mv = fmaxf(mv, __shfl_xor(mv, 16)); \
    mv = fmaxf(mv, __shfl_xor(mv, 32)); \
    if (quad == 0) out[(m0 + w) * 256 + col] = mv; }

    // ==== GEMM3: out = maxpool(relu(h2 @ W3 + b3)), K=128, N=256, 16 steps, 2-deep ====
    {
        bf16x8 a3[4][2];
        #pragma unroll
        for (int ki = 0; ki < 4; ki++)
            #pragma unroll
            for (int t = 0; t < 2; t++) {
                int row = r0 + t * 16 + m16;
                a3[ki][t] = __builtin_bit_cast(bf16x8, sA4[row * 16 + ((ki * 4 + quad) ^ (row & 7))]);
            }
        uint4 p0[4], p1[4];
        #pragma unroll
        for (int ki = 0; ki < 4; ki++) p0[ki] = LDB(16, ki * 4 + quad, W3, 256, m16, 128);
        #pragma unroll
        for (int ki = 0; ki < 4; ki++) p1[ki] = LDB(17, ki * 4 + quad, W3, 256, 16 + m16, 128);
        #pragma unroll
        for (int s = 0; s < 16; s += 2) {
            {
                floatx4 acc[2] = {vzero, vzero};
                __builtin_amdgcn_s_setprio(1);
                #pragma unroll
                for (int ki = 0; ki < 4; ki++) {
                    bf16x8 b = __builtin_bit_cast(bf16x8, p0[ki]);
                    #pragma unroll
                    for (int t = 0; t < 2; t++)
                        acc[t] = __builtin_amdgcn_mfma_f32_16x16x32_bf16(a3[ki][t], b, acc[t], 0, 0, 0);
                }
                __builtin_amdgcn_s_setprio(0);
                if (s + 2 < 16) {
                    #pragma unroll
                    for (int ki = 0; ki < 4; ki++)
                        p0[ki] = LDB(16 + s + 2, ki * 4 + quad, W3, 256, (s + 2) * 16 + m16, 128);
                }
                EPI3(s, acc);
            }
            {
                floatx4 acc[2] = {vzero, vzero};
                __builtin_amdgcn_s_setprio(1);
                #pragma unroll
                for (int ki = 0; ki < 4; ki++) {
                    bf16x8 b = __builtin_bit_cast(bf16x8, p1[ki]);
                    #pragma unroll
                    for (int t = 0; t < 2; t++)
                        acc[t] = __builtin_amdgcn_mfma_f32_16x16x32_bf16(a3[ki][t], b, acc[t], 0, 0, 0);
                }
                __builtin_amdgcn_s_setprio(0);
                if (s + 3 < 16) {
                    #pragma unroll
                    for (int ki = 0; ki < 4; ki++)
                        p1[ki] = LDB(16 + s + 3, ki * 4 + quad, W3, 256, (s + 3) * 16 + m16, 128);
                }
                EPI3(s + 1, acc);
            }
        }
    }
#undef LDB
#undef EPI12
#undef EPI3
}

extern "C" void kernel_launch(void* const* d_in, const int* in_sizes, int n_in,
                              void* d_out, int out_size, void* d_ws, size_t ws_size,
                              hipStream_t stream) {
    const float* x     = (const float*)d_in[0];
    const float* pos   = (const float*)d_in[1];
    const int*   batch = (const int*)d_in[2];
    const int*   idx   = (const int*)d_in[3];
    const float* W1    = (const float*)d_in[4];
    const float* b1    = (const float*)d_in[5];
    const float* W2    = (const float*)d_in[6];
    const float* b2    = (const float*)d_in[7];
    const float* W3    = (const float*)d_in[8];
    const float* b3    = (const float*)d_in[9];
    float* out = (float*)d_out;
    uint4* ws4 = (uint4*)d_ws;

    if (ws_size >= 131072) {
        hipLaunchKernelGGL(prep_kernel, dim3(32), dim3(256), 0, stream, W1, W2, W3, ws4);
        hipLaunchKernelGGL((sa_kernel<true>), dim3(MCENT / WAVES), dim3(512), 0, stream,
                           x, pos, batch, idx, W1, b1, W2, b2, W3, b3, ws4, out);
    } else {
        hipLaunchKernelGGL((sa_kernel<false>), dim3(MCENT / WAVES), dim3(512), 0, stream,
                           x, pos, batch, idx, W1, b1, W2, b2, W3, b3, ws4, out);
    }
}

// Round 9
// 162.739 us; speedup vs baseline: 1.0126x; 1.0126x over previous
//
#include <hip/hip_runtime.h>

// SAModule (PointNet++ SA), fused f32-input kernel. R14:
//  - R13 post-mortem: 16 launchable waves still measured ~11 (35%) => TLP lever closed;
//    duration tracks issued instructions. Corrected accounting: phase-A hit body fires
//    ~89% of tests (any-lane semantics) ~650 inst/wave; EPI3 mask+bias ~480.
//  - R14 instruction cuts (no structural change):
//    * duplicate-neighbor padding (max-aggregation invariant): rows >= nsel take lane-0's
//      neighbor => EPI3 nsel-mask deleted, gather zero-branch deleted
//    * EPI3: reduce-then-bias-then-relu (bias is column-constant): ~13 inst/step vs ~30
//    * lean hit body: d2 clamped >= 0 => raw float bits are monotone keys (no sign-flip)

typedef unsigned short u16;
typedef unsigned int u32;
typedef unsigned long long u64;
typedef __bf16 bf16x8 __attribute__((ext_vector_type(8)));
typedef float floatx4 __attribute__((ext_vector_type(4)));

#define PCLOUD 4096
#define DIN    64
#define MCENT  8192
#define KNBR   32
#define CAP    448
#define WAVES  8

// smem map (65536 B): sA = 256 rows x 256B. phase A/B overlay (dead before gather):
#define OFF_LIST  0        // u64[8][CAP] = 28672
#define OFF_HIST  28672    // u32[8][32]  = 1024
#define OFF_NBRL  29696    // int[8][32]  = 1024
#define OFF_CNT   30720    // int[8] acnt | int[8] cnt2
#define OFF_CEN   30784    // float4[8] centers (x,y,z,|c|^2)
#define OFF_BCL   30912    // int[8] cloud ids

__device__ inline u16 f2bf(float f) {          // RNE, no scrub (inputs finite)
    u32 b = __float_as_uint(f);
    b += 0x7fffu + ((b >> 16) & 1u);
    return (u16)(b >> 16);
}
__device__ inline u32 cvtpk(float a, float b) {  // packed {bf16(a), bf16(b)<<16}, RNE
    u32 r;
    asm("v_cvt_pk_bf16_f32 %0, %1, %2" : "=v"(r) : "v"(a), "v"(b));
    return r;
}
__device__ inline u64 wave_min_u64(u64 v) {
    #pragma unroll
    for (int off = 32; off; off >>= 1) {
        u64 o = __shfl_xor((unsigned long long)v, off);
        if (o < v) v = o;
    }
    return v;
}
// density-equalized bucket over raw-bits keys (d2 >= 0): count/bucket ~ const, monotone.
__device__ inline int key_bucket(u64 k) {
    float d2 = __uint_as_float((u32)(k >> 32));
    float t = d2 * 25.0f;                              // d2/R2, [0,1]
    float b = 32.0f * t * __builtin_sqrtf(t);          // 32 * t^1.5
    int bi = (int)b;
    return bi > 31 ? 31 : bi;
}

// ---- prep: weights -> bf16 B-fragment images in ws (consumed directly from L2) ----
// 32 contiguous 4KB blocks of 16 cols each: blk 0..7 = W1, 8..15 = W2, 16..31 = W3.
// blk layout (256 uint4): chunk[n*16 + (kc^(n&7))] = {bf16 W[kc*8+j][col0+n], j=0..7}
__global__ void prep_kernel(const float* __restrict__ W1, const float* __restrict__ W2,
                            const float* __restrict__ W3, uint4* __restrict__ ws) {
    int t = blockIdx.x * 256 + threadIdx.x;   // 0..8191
    int g = t >> 11, r = t & 2047;
    int n = r >> 4, kc = r & 15;
    const float* W; int rs, n0, krows;
    if (g == 0)      { W = W1; rs = 128; n0 = 0;   krows = 67;  }
    else if (g == 1) { W = W2; rs = 128; n0 = 0;   krows = 128; }
    else if (g == 2) { W = W3; rs = 256; n0 = 0;   krows = 128; }
    else             { W = W3; rs = 256; n0 = 128; krows = 128; }
    u16 e[8];
    #pragma unroll
    for (int j = 0; j < 8; j++) {
        int k = kc * 8 + j;
        e[j] = (k < krows) ? f2bf(W[(size_t)k * rs + n0 + n]) : (u16)0;
    }
    ws[(g << 11) + (n << 4) + (kc ^ (n & 7))] = *(const uint4*)e;
}

// One B-fragment (8 bf16 of col `col0+m16`, k-rows cb*8..cb*8+7), straight from ws/L2.
__device__ __forceinline__ uint4 ldB_ws(const uint4* __restrict__ ws4, int blk, int cb, int m16) {
    return ws4[blk * 256 + (m16 << 4) + (cb ^ (m16 & 7))];
}
// Workspace-less fallback: gather the column from W in f32 and pack (correctness path).
__device__ __forceinline__ uint4 ldB_fb(const float* __restrict__ W, int rs, int col,
                                        int cb, int krows) {
    u16 e[8];
    #pragma unroll
    for (int j = 0; j < 8; j++) {
        int k = cb * 8 + j;
        e[j] = (k < krows) ? f2bf(W[(size_t)k * rs + col]) : (u16)0;
    }
    return *(const uint4*)e;
}

// Lean hit push: clamp d2>=0 (self-point FMA noise), raw-bits monotone key.
__device__ __forceinline__ void push_hit(int c, float d2, int j,
                                         int* acnt, u64* lists) {
    int p = atomicAdd(&acnt[c], 1);
    u64 key = ((u64)__float_as_uint(fmaxf(d2, 0.0f)) << 32) | (u32)j;
    if (p < CAP) lists[c * CAP + p] = key;
}

template <bool WS>
__global__ __launch_bounds__(512, 4) void sa_kernel(
    const float* __restrict__ x, const float* __restrict__ pos,
    const int* __restrict__ batch, const int* __restrict__ idx,
    const float* __restrict__ W1, const float* __restrict__ b1,
    const float* __restrict__ W2, const float* __restrict__ b2,
    const float* __restrict__ W3, const float* __restrict__ b3,
    const uint4* __restrict__ ws4, float* __restrict__ out) {
    __shared__ __align__(16) char smem[65536];
    u64*  lists = (u64*)(smem + OFF_LIST);
    u32*  hist  = (u32*)(smem + OFF_HIST);
    int*  nbrl  = (int*)(smem + OFF_NBRL);
    int*  acnt  = (int*)(smem + OFF_CNT);
    int*  cnt2  = (int*)(smem + OFF_CNT + 32);
    float4* cen = (float4*)(smem + OFF_CEN);
    int*  bcls  = (int*)(smem + OFF_BCL);
    uint4* sA4  = (uint4*)smem;

    int tid = threadIdx.x, w = tid >> 6, l = tid & 63;
    int bid = blockIdx.x;
    int m0 = ((bid & 7) << 10) + ((bid >> 3) << 3);   // XCD-friendly: bid%8 ~ cloud
    int m = m0 + w;
    int ic = idx[m] & (8 * PCLOUD - 1);
    float cx = pos[ic * 3], cy = pos[ic * 3 + 1], cz = pos[ic * 3 + 2];
    float sc = __fadd_rn(__fadd_rn(__fmul_rn(cx, cx), __fmul_rn(cy, cy)), __fmul_rn(cz, cz));
    int bcl = batch[ic] & 7;
    int base = bcl << 12;
    const float R2 = 0.04f;

    if (l == 0) { cen[w] = make_float4(cx, cy, cz, sc); bcls[w] = bcl; }
    if (tid < WAVES) { acnt[tid] = 0; cnt2[tid] = 0; }
    if (l == 1) {
        float* o1 = out + MCENT * 256;
        o1[m * 3] = cx; o1[m * 3 + 1] = cy; o1[m * 3 + 2] = cz;
        (o1 + MCENT * 3)[m] = (float)bcl;
    }
    __syncthreads();

    // ---- phase A: cooperative scan, float4 loads, FMA-contracted tests vs 8 centers ----
    bool uni = true;
    #pragma unroll
    for (int cc = 1; cc < WAVES; cc++) uni = uni && (bcls[cc] == bcls[0]);
    if (uni) {
        float4 cw[WAVES];
        float nx[WAVES], ny[WAVES], nz[WAVES];
        #pragma unroll
        for (int cc = 0; cc < WAVES; cc++) {
            cw[cc] = cen[cc];
            nx[cc] = -2.0f * cw[cc].x; ny[cc] = -2.0f * cw[cc].y; nz[cc] = -2.0f * cw[cc].z;
        }
        int jb = bcls[0] << 12;
        const float4* pb4 = (const float4*)(pos + (size_t)jb * 3);

#define TESTP(PX, PY, PZ, J) { \
    float sp = __builtin_fmaf((PX), (PX), __builtin_fmaf((PY), (PY), (PZ) * (PZ))); \
    _Pragma("unroll") \
    for (int cc = 0; cc < WAVES; cc++) { \
        float d2 = __builtin_fmaf(nx[cc], (PX), __builtin_fmaf(ny[cc], (PY), \
                   __builtin_fmaf(nz[cc], (PZ), cw[cc].w + sp))); \
        if (d2 <= R2) push_hit(cc, d2, (J), acnt, lists); \
    } }

        #pragma unroll
        for (int it = 0; it < 2; it++) {
            int tq = it * 512 + tid;                   // quad-point index 0..1023
            float4 q0 = pb4[tq * 3], q1 = pb4[tq * 3 + 1], q2 = pb4[tq * 3 + 2];
            int j0 = jb + tq * 4;
            TESTP(q0.x, q0.y, q0.z, j0)
            TESTP(q0.w, q1.x, q1.y, j0 + 1)
            TESTP(q1.z, q1.w, q2.x, j0 + 2)
            TESTP(q2.y, q2.z, q2.w, j0 + 3)
        }
#undef TESTP
    } else {
        // rare mixed-cloud block: per-wave scan of own cloud from global (FMA form)
        float nx = -2.0f * cx, ny = -2.0f * cy, nz = -2.0f * cz;
        for (int t = l; t < PCLOUD; t += 64) {
            int j = base + t;
            float px = pos[j * 3], py = pos[j * 3 + 1], pz = pos[j * 3 + 2];
            float sp = __builtin_fmaf(px, px, __builtin_fmaf(py, py, pz * pz));
            float d2 = __builtin_fmaf(nx, px, __builtin_fmaf(ny, py,
                       __builtin_fmaf(nz, pz, sc + sp)));
            if (d2 <= R2) push_hit(w, d2, j, acnt, lists);
        }
    }
    __syncthreads();   // cross-wave list visibility

    int c = acnt[w];
    u64* mylist = lists + w * CAP;

    // ---- phase B: select the 32 smallest (d2,idx) keys (set only; order free) ----
    int selj = -1;
    if (c <= KNBR) {
        if (l < c) selj = (int)(u32)mylist[l];
    } else if (c <= CAP) {
        u64 kk[7];
        int bk[7];
        if (l < 32) hist[w * 32 + l] = 0;              // same-wave LDS: ordered
        #pragma unroll
        for (int i = 0; i < 7; i++) kk[i] = (l + i * 64 < c) ? mylist[l + i * 64] : ~0ull;
        #pragma unroll
        for (int i = 0; i < 7; i++) {                  // build d2 histogram (this wave only)
            bk[i] = 32;
            if (kk[i] != ~0ull) {
                bk[i] = key_bucket(kk[i]);
                atomicAdd(&hist[w * 32 + bk[i]], 1u);
            }
        }
        int hv = (l < 32) ? (int)hist[w * 32 + l] : 0; // atomics above are same-wave: ordered
        #pragma unroll
        for (int off = 1; off <= 16; off <<= 1) {   // inclusive scan, lanes 0..31
            int o = __shfl_up(hv, off);
            if (l >= off) hv += o;
        }
        u64 ge = __ballot((l < 32) && (hv >= KNBR));
        int B = __ffsll((unsigned long long)ge) - 1;        // threshold bucket
        int S = (B == 0) ? 0 : __shfl(hv, B - 1);           // count strictly below B
        #pragma unroll
        for (int i = 0; i < 7; i++) {                       // bulk-select below B
            if (kk[i] != ~0ull) {
                if (bk[i] < B) { int p = atomicAdd(&cnt2[w], 1); nbrl[w * 32 + p] = (int)(u32)kk[i]; }
                if (bk[i] != B) kk[i] = ~0ull;              // keep only bucket-B keys
            }
        }
        int need = KNBR - S;                                // equalized buckets: ~1-4 rounds
        u64 last = 0;
        for (int r = 0; r < need; r++) {
            u64 mn = ~0ull;
            #pragma unroll
            for (int i = 0; i < 7; i++) if (kk[i] > last && kk[i] < mn) mn = kk[i];
            mn = wave_min_u64(mn);
            if (l == 0) nbrl[w * 32 + S + r] = (int)(u32)mn;
            last = mn;
        }
        if (l < KNBR) selj = nbrl[w * 32 + l];
    } else {
        // overflow fallback (never taken for uniform data): streaming 32-round argmin
        float nx = -2.0f * cx, ny = -2.0f * cy, nz = -2.0f * cz;
        u64 last = 0;
        for (int r = 0; r < KNBR; r++) {
            u64 mn = ~0ull;
            for (int t = l; t < PCLOUD; t += 64) {
                int j = base + t;
                float px = pos[j * 3], py = pos[j * 3 + 1], pz = pos[j * 3 + 2];
                float sp = __builtin_fmaf(px, px, __builtin_fmaf(py, py, pz * pz));
                float d2 = __builtin_fmaf(nx, px, __builtin_fmaf(ny, py,
                           __builtin_fmaf(nz, pz, sc + sp)));
                if (d2 <= R2) {
                    u64 kf = ((u64)__float_as_uint(fmaxf(d2, 0.0f)) << 32) | (u32)j;
                    if (kf > last && kf < mn) mn = kf;
                }
            }
            mn = wave_min_u64(mn);
            if (l == r) selj = (int)(u32)mn;
            last = mn;
        }
    }
    // duplicate-pad: rows beyond the valid count take lane-0's neighbor. MAX aggregation
    // is invariant under duplicates, so the nsel mask disappears downstream. c>=1 always
    // (the center itself is in its own ball), so lane 0 is valid.
    {
        int s0 = __shfl(selj, 0);
        if (selj < 0) selj = s0;
    }
    __syncthreads();   // LAST barrier: lists/hist dead; sA becomes the (wave-private) A-tile

    // ---- gather 32 feat rows per wave (XOR 16B-chunk swizzle); rows are wave-private.
    //      All rows valid (duplicate-padded); h-branched compile-time unroll.
    {
        int h = l & 1, rl = l >> 1;
        int row = w * 32 + rl;
        int j = __shfl(selj, rl);
        int xv = row & 7;
        uint4* dst = sA4 + row * 16;
        const float4* sx = (const float4*)(x + (size_t)j * DIN);
        if (h == 0) {
            float4 f[12];
            #pragma unroll
            for (int i = 0; i < 12; i++) f[i] = sx[i];
            #pragma unroll
            for (int c0 = 0; c0 < 6; c0++) {
                uint4 pv;
                pv.x = cvtpk(f[c0 * 2].x, f[c0 * 2].y);
                pv.y = cvtpk(f[c0 * 2].z, f[c0 * 2].w);
                pv.z = cvtpk(f[c0 * 2 + 1].x, f[c0 * 2 + 1].y);
                pv.w = cvtpk(f[c0 * 2 + 1].z, f[c0 * 2 + 1].w);
                dst[c0 ^ xv] = pv;
            }
        } else {
            uint4 z; z.x = z.y = z.z = z.w = 0;
            float4 f[4];
            #pragma unroll
            for (int i = 0; i < 4; i++) f[i] = sx[12 + i];
            float rx = pos[j * 3] - cx, ry = pos[j * 3 + 1] - cy, rz = pos[j * 3 + 2] - cz;
            #pragma unroll
            for (int c0 = 0; c0 < 2; c0++) {
                uint4 pv;
                pv.x = cvtpk(f[c0 * 2].x, f[c0 * 2].y);
                pv.y = cvtpk(f[c0 * 2].z, f[c0 * 2].w);
                pv.z = cvtpk(f[c0 * 2 + 1].x, f[c0 * 2 + 1].y);
                pv.w = cvtpk(f[c0 * 2 + 1].z, f[c0 * 2 + 1].w);
                dst[(6 + c0) ^ xv] = pv;
            }
            uint4 rc; rc.x = cvtpk(rx, ry); rc.y = cvtpk(rz, 0.0f); rc.z = 0; rc.w = 0;
            dst[8 ^ xv] = rc;
            dst[9 ^ xv] = z; dst[10 ^ xv] = z; dst[11 ^ xv] = z;
        }
    }

    int m16 = l & 15, quad = l >> 4;
    int r0 = w * 32;
    const floatx4 vzero = {0.f, 0.f, 0.f, 0.f};

#define LDB(BLK, CB, W, RS, COL, KR) \
    (WS ? ldB_ws(ws4, (BLK), (CB), m16) : ldB_fb((W), (RS), (COL), (CB), (KR)))

// h-epilogue for GEMM1/2: relu(acc+bias) -> bf16 pair writes into swizzled sA rows
#define EPI12(BPTR, S, ACC) { \
    float4 bb = ((const float4*)(BPTR))[(S) * 4 + quad]; \
    _Pragma("unroll") \
    for (int t = 0; t < 2; t++) { \
        int rr = r0 + t * 16 + m16; \
        uint2 pv; \
        pv.x = cvtpk(fmaxf(ACC[t][0] + bb.x, 0.f), fmaxf(ACC[t][1] + bb.y, 0.f)); \
        pv.y = cvtpk(fmaxf(ACC[t][2] + bb.z, 0.f), fmaxf(ACC[t][3] + bb.w, 0.f)); \
        *(uint2*)(smem + rr * 256 + ((((S) * 2 + (quad >> 1)) ^ (rr & 7)) << 4) + ((quad & 1) << 3)) = pv; \
    } }

    // ==== GEMM1: h1 = relu(feat @ W1 + b1), K=96, swapped operands, 8 steps, 2-deep ====
    {
        bf16x8 a1[3][2];
        #pragma unroll
        for (int ki = 0; ki < 3; ki++)
            #pragma unroll
            for (int t = 0; t < 2; t++) {
                int row = r0 + t * 16 + m16;
                a1[ki][t] = __builtin_bit_cast(bf16x8, sA4[row * 16 + ((ki * 4 + quad) ^ (row & 7))]);
            }
        uint4 p0[3], p1[3];
        #pragma unroll
        for (int ki = 0; ki < 3; ki++) p0[ki] = LDB(0, ki * 4 + quad, W1, 128, m16, 67);
        #pragma unroll
        for (int ki = 0; ki < 3; ki++) p1[ki] = LDB(1, ki * 4 + quad, W1, 128, 16 + m16, 67);
        #pragma unroll
        for (int s = 0; s < 8; s += 2) {
            {
                floatx4 acc[2] = {vzero, vzero};
                __builtin_amdgcn_s_setprio(1);
                #pragma unroll
                for (int ki = 0; ki < 3; ki++) {
                    bf16x8 b = __builtin_bit_cast(bf16x8, p0[ki]);
                    #pragma unroll
                    for (int t = 0; t < 2; t++)
                        acc[t] = __builtin_amdgcn_mfma_f32_16x16x32_bf16(b, a1[ki][t], acc[t], 0, 0, 0);
                }
                __builtin_amdgcn_s_setprio(0);
                if (s + 2 < 8) {
                    #pragma unroll
                    for (int ki = 0; ki < 3; ki++)
                        p0[ki] = LDB(s + 2, ki * 4 + quad, W1, 128, (s + 2) * 16 + m16, 67);
                }
                EPI12(b1, s, acc);
            }
            {
                floatx4 acc[2] = {vzero, vzero};
                __builtin_amdgcn_s_setprio(1);
                #pragma unroll
                for (int ki = 0; ki < 3; ki++) {
                    bf16x8 b = __builtin_bit_cast(bf16x8, p1[ki]);
                    #pragma unroll
                    for (int t = 0; t < 2; t++)
                        acc[t] = __builtin_amdgcn_mfma_f32_16x16x32_bf16(b, a1[ki][t], acc[t], 0, 0, 0);
                }
                __builtin_amdgcn_s_setprio(0);
                if (s + 3 < 8) {
                    #pragma unroll
                    for (int ki = 0; ki < 3; ki++)
                        p1[ki] = LDB(s + 3, ki * 4 + quad, W1, 128, (s + 3) * 16 + m16, 67);
                }
                EPI12(b1, s + 1, acc);
            }
        }
    }

    // ==== GEMM2: h2 = relu(h1 @ W2 + b2), K=128, swapped operands, 8 steps, 2-deep ====
    {
        bf16x8 a2[4][2];
        #pragma unroll
        for (int ki = 0; ki < 4; ki++)
            #pragma unroll
            for (int t = 0; t < 2; t++) {
                int row = r0 + t * 16 + m16;
                a2[ki][t] = __builtin_bit_cast(bf16x8, sA4[row * 16 + ((ki * 4 + quad) ^ (row & 7))]);
            }
        uint4 p0[4], p1[4];
        #pragma unroll
        for (int ki = 0; ki < 4; ki++) p0[ki] = LDB(8, ki * 4 + quad, W2, 128, m16, 128);
        #pragma unroll
        for (int ki = 0; ki < 4; ki++) p1[ki] = LDB(9, ki * 4 + quad, W2, 128, 16 + m16, 128);
        #pragma unroll
        for (int s = 0; s < 8; s += 2) {
            {
                floatx4 acc[2] = {vzero, vzero};
                __builtin_amdgcn_s_setprio(1);
                #pragma unroll
                for (int ki = 0; ki < 4; ki++) {
                    bf16x8 b = __builtin_bit_cast(bf16x8, p0[ki]);
                    #pragma unroll
                    for (int t = 0; t < 2; t++)
                        acc[t] = __builtin_amdgcn_mfma_f32_16x16x32_bf16(b, a2[ki][t], acc[t], 0, 0, 0);
                }
                __builtin_amdgcn_s_setprio(0);
                if (s + 2 < 8) {
                    #pragma unroll
                    for (int ki = 0; ki < 4; ki++)
                        p0[ki] = LDB(8 + s + 2, ki * 4 + quad, W2, 128, (s + 2) * 16 + m16, 128);
                }
                EPI12(b2, s, acc);
            }
            {
                floatx4 acc[2] = {vzero, vzero};
                __builtin_amdgcn_s_setprio(1);
                #pragma unroll
                for (int ki = 0; ki < 4; ki++) {
                    bf16x8 b = __builtin_bit_cast(bf16x8, p1[ki]);
                    #pragma unroll
                    for (int t = 0; t < 2; t++)
                        acc[t] = __builtin_amdgcn_mfma_f32_16x16x32_bf16(b, a2[ki][t], acc[t], 0, 0, 0);
                }
                __builtin_amdgcn_s_setprio(0);
                if (s + 3 < 8) {
                    #pragma unroll
                    for (int ki = 0; ki < 4; ki++)
                        p1[ki] = LDB(8 + s + 3, ki * 4 + quad, W2, 128, (s + 3) * 16 + m16, 128);
                }
                EPI12(b2, s + 1, acc);
            }
        }
    }

// GEMM3 epilogue: unmasked max over this wave's 32 rows (duplicate-padded), then
// bias+relu once (column-constant bias commutes with max; relu is monotone).
#define EPI3(S, ACC) { \
    int col = (S) * 16 + m16; \
    float mv = fmaxf(fmaxf(fmaxf(ACC[0][0], ACC[0][1]), fmaxf(ACC[0][2], ACC[0][3])), \
                     fmaxf(fmaxf(ACC[1][0], ACC[1][1]), fmaxf(ACC[1][2], ACC[1][3]))); \
    mv = fmaxf(mv, __shfl_xor(mv, 16)); \
    mv = fmaxf(mv, __shfl_xor(mv, 32)); \
    mv = fmaxf(mv + b3[col], 0.0f); \
    if (quad == 0) out[(m0 + w) * 256 + col] = mv; }

    // ==== GEMM3: out = maxpool(relu(h2 @ W3 + b3)), K=128, N=256, 16 steps, 2-deep ====
    {
        bf16x8 a3[4][2];
        #pragma unroll
        for (int ki = 0; ki < 4; ki++)
            #pragma unroll
            for (int t = 0; t < 2; t++) {
                int row = r0 + t * 16 + m16;
                a3[ki][t] = __builtin_bit_cast(bf16x8, sA4[row * 16 + ((ki * 4 + quad) ^ (row & 7))]);
            }
        uint4 p0[4], p1[4];
        #pragma unroll
        for (int ki = 0; ki < 4; ki++) p0[ki] = LDB(16, ki * 4 + quad, W3, 256, m16, 128);
        #pragma unroll
        for (int ki = 0; ki < 4; ki++) p1[ki] = LDB(17, ki * 4 + quad, W3, 256, 16 + m16, 128);
        #pragma unroll
        for (int s = 0; s < 16; s += 2) {
            {
                floatx4 acc[2] = {vzero, vzero};
                __builtin_amdgcn_s_setprio(1);
                #pragma unroll
                for (int ki = 0; ki < 4; ki++) {
                    bf16x8 b = __builtin_bit_cast(bf16x8, p0[ki]);
                    #pragma unroll
                    for (int t = 0; t < 2; t++)
                        acc[t] = __builtin_amdgcn_mfma_f32_16x16x32_bf16(a3[ki][t], b, acc[t], 0, 0, 0);
                }
                __builtin_amdgcn_s_setprio(0);
                if (s + 2 < 16) {
                    #pragma unroll
                    for (int ki = 0; ki < 4; ki++)
                        p0[ki] = LDB(16 + s + 2, ki * 4 + quad, W3, 256, (s + 2) * 16 + m16, 128);
                }
                EPI3(s, acc);
            }
            {
                floatx4 acc[2] = {vzero, vzero};
                __builtin_amdgcn_s_setprio(1);
                #pragma unroll
                for (int ki = 0; ki < 4; ki++) {
                    bf16x8 b = __builtin_bit_cast(bf16x8, p1[ki]);
                    #pragma unroll
                    for (int t = 0; t < 2; t++)
                        acc[t] = __builtin_amdgcn_mfma_f32_16x16x32_bf16(a3[ki][t], b, acc[t], 0, 0, 0);
                }
                __builtin_amdgcn_s_setprio(0);
                if (s + 3 < 16) {
                    #pragma unroll
                    for (int ki = 0; ki < 4; ki++)
                        p1[ki] = LDB(16 + s + 3, ki * 4 + quad, W3, 256, (s + 3) * 16 + m16, 128);
                }
                EPI3(s + 1, acc);
            }
        }
    }
#undef LDB
#undef EPI12
#undef EPI3
}

extern "C" void kernel_launch(void* const* d_in, const int* in_sizes, int n_in,
                              void* d_out, int out_size, void* d_ws, size_t ws_size,
                              hipStream_t stream) {
    const float* x     = (const float*)d_in[0];
    const float* pos   = (const float*)d_in[1];
    const int*   batch = (const int*)d_in[2];
    const int*   idx   = (const int*)d_in[3];
    const float* W1    = (const float*)d_in[4];
    const float* b1    = (const float*)d_in[5];
    const float* W2    = (const float*)d_in[6];
    const float* b2    = (const float*)d_in[7];
    const float* W3    = (const float*)d_in[8];
    const float* b3    = (const float*)d_in[9];
    float* out = (float*)d_out;
    uint4* ws4 = (uint4*)d_ws;

    if (ws_size >= 131072) {
        hipLaunchKernelGGL(prep_kernel, dim3(32), dim3(256), 0, stream, W1, W2, W3, ws4);
        hipLaunchKernelGGL((sa_kernel<true>), dim3(MCENT / WAVES), dim3(512), 0, stream,
                           x, pos, batch, idx, W1, b1, W2, b2, W3, b3, ws4, out);
    } else {
        hipLaunchKernelGGL((sa_kernel<false>), dim3(MCENT / WAVES), dim3(512), 0, stream,
                           x, pos, batch, idx, W1, b1, W2, b2, W3, b3, ws4, out);
    }
}